// Round 7
// baseline (101.268 us; speedup 1.0000x reference)
//
#include <hip/hip_runtime.h>
#include <math.h>

#define BS    128
#define NE    512
#define F     6
#define NH    4
#define DPH   4
#define NEMBD 16

#define CH    8
#define CPAD  33   // float4 stride/chunk: 8 broadcast addrs cover all 32 banks (mod math = r2-r6 proven)

#if __has_builtin(__builtin_amdgcn_exp2f)
#define EXP2(x) __builtin_amdgcn_exp2f(x)
#else
#define EXP2(x) exp2f(x)
#endif

typedef float v2f __attribute__((ext_vector_type(2)));

// ---------------------------------------------------------------------------
// attention, K-split: 1024 blocks = (b, h, kh), 512 threads. Block (b,h,kh)
// processes ALL query rows against key-half kh (entities [256kh, 256kh+256)),
// writing UNSCALED partials (sum_e, sum_e*v, l_partial) to ws; epi merges the
// two halves exactly (pure reassociation of the same fp32 sums).
// Active-entity compaction as r6, but slot bases come from a deterministic
// LDS exclusive scan of per-wave ballot counts (no atomic ordering).
// Keys of half kh compacted into 8 chunks x L keys (L = ceil(Nk_h/8) ~ 26);
// zero-padded tail slots contribute e=exp2(0)=1, subtracted via padcorr.
// No-max softmax (exact-verified rounds 1-6). q computed once per row in LDS.
// ---------------------------------------------------------------------------
__global__ __launch_bounds__(512) void attn_kernel(
    const float* __restrict__ inp, const float* __restrict__ mask,
    const float* __restrict__ Wq, const float* __restrict__ Wk,
    const float* __restrict__ Wv,
    float4* __restrict__ attp, float* __restrict__ lp)
{
    const int b    = blockIdx.x >> 3;
    const int h    = (blockIdx.x >> 1) & 3;
    const int kh   = blockIdx.x & 1;
    const int t    = threadIdx.x;
    const int c    = t & 7;
    const int g    = t >> 3;
    const int w    = t >> 6;
    const int lane = t & 63;

    __shared__ float4 sk[CH * CPAD];
    __shared__ float4 sv[CH * CPAD];
    __shared__ float4 sq[576];            // row-slot s at sq[9*(s>>3) + (s&7)]
    __shared__ unsigned short rlist[512]; // compacted slot -> entity id
    __shared__ int wcnt[8];               // per-wave active counts

    // ---- zero init ----
    const float4 z4 = make_float4(0.f, 0.f, 0.f, 0.f);
    if (t < CH * CPAD) { sk[t] = z4; sv[t] = z4; }
    sq[9 * g + c] = z4;

    const float me = mask[b * NE + t];
    const bool act = me > 0.f;            // mask is exactly 0.0 or 1.0

    // ---- per-wave ballot counts (deterministic compaction) ----
    const unsigned long long ball = __ballot(act);
    const int prefix = __builtin_amdgcn_mbcnt_hi((unsigned int)(ball >> 32),
                        __builtin_amdgcn_mbcnt_lo((unsigned int)ball, 0));
    if (lane == 0) wcnt[w] = (int)__popcll(ball);

    __syncthreads();   // B1: zeros + wcnt visible

    // ---- exclusive scans over the 8 wave counts ----
    int rbase = 0, Nk = 0, Nk_h = 0, kbase = 0;
    #pragma unroll
    for (int u = 0; u < 8; ++u) {
        const int cu = wcnt[u];
        Nk += cu;
        if (u < w) rbase += cu;
        if ((u >> 2) == kh) {
            Nk_h += cu;
            if (u < w) kbase += cu;
        }
    }
    const int L = (Nk_h + 7) >> 3;                 // keys per chunk
    const float padcorr = (float)(8 * L - Nk_h);   // zero-pad slots give e=1

    // ---- staging: q for every active entity; K/V only for this key-half ----
    if (act) {
        const int s = rbase + prefix;              // global row slot
        const float2* rp = (const float2*)(inp + ((size_t)(b * NE + t)) * F);
        const float2 r0 = rp[0], r1 = rp[1], r2 = rp[2];
        const float x0 = r0.x, x1 = r0.y, x2 = r1.x,
                    x3 = r1.y, x4 = r2.x, x5 = r2.y;   // mask=1: no scaling
        const float QS = 0.5f * 1.44269504088896340736f;  // 1/sqrt(4)*log2(e)
        const float* wq = Wq + h * DPH * F;
        float qq[4];
        #pragma unroll
        for (int d = 0; d < DPH; ++d) {
            const float* wd = wq + d * F;
            qq[d] = QS * (x0*wd[0] + x1*wd[1] + x2*wd[2] + x3*wd[3] + x4*wd[4] + x5*wd[5]);
        }
        sq[9 * (s >> 3) + (s & 7)] = make_float4(qq[0], qq[1], qq[2], qq[3]);
        rlist[s] = (unsigned short)t;

        if ((w >> 2) == kh) {                      // entity in this key-half
            const int ks = kbase + prefix;         // half-local key slot
            const float* wk = Wk + h * DPH * F;
            const float* wv = Wv + h * DPH * F;
            float kk[4], vv[4];
            #pragma unroll
            for (int d = 0; d < DPH; ++d) {
                const float* wd = wk + d * F;
                kk[d] = x0*wd[0] + x1*wd[1] + x2*wd[2] + x3*wd[3] + x4*wd[4] + x5*wd[5];
                wd = wv + d * F;
                vv[d] = x0*wd[0] + x1*wd[1] + x2*wd[2] + x3*wd[3] + x4*wd[4] + x5*wd[5];
            }
            sk[(ks & 7) * CPAD + (ks >> 3)] = make_float4(kk[0], kk[1], kk[2], kk[3]);
            sv[(ks & 7) * CPAD + (ks >> 3)] = make_float4(vv[0], vv[1], vv[2], vv[3]);
        }
    }

    __syncthreads();   // B2: sk/sv/sq/rlist visible

    // ---- wave-granular row skip ----
    if (64 * w >= Nk) return;

    // ---- load q for row-slots 8g..8g+7 (broadcast b128, conflict-free) ----
    float4 qa[8];
    #pragma unroll
    for (int r = 0; r < 8; ++r) qa[r] = sq[9 * g + r];
    v2f qv[4][DPH];
    #pragma unroll
    for (int p = 0; p < 4; ++p) {
        qv[p][0] = (v2f){qa[2*p].x, qa[2*p+1].x};
        qv[p][1] = (v2f){qa[2*p].y, qa[2*p+1].y};
        qv[p][2] = (v2f){qa[2*p].z, qa[2*p+1].z};
        qv[p][3] = (v2f){qa[2*p].w, qa[2*p+1].w};
    }

    // ---- inner loop: L keys of chunk c x 4 packed row pairs ----
    const float4* kb = sk + c * CPAD;
    const float4* vb = sv + c * CPAD;
    v2f l2[4], a2[4][DPH];
    #pragma unroll
    for (int p = 0; p < 4; ++p) {
        l2[p] = (v2f)(0.f);
        #pragma unroll
        for (int d = 0; d < DPH; ++d) a2[p][d] = (v2f)(0.f);
    }

    #pragma unroll 4
    for (int j = 0; j < L; ++j) {
        const float4 kv = kb[j];
        const float4 uv = vb[j];
        const v2f kx = (v2f){kv.x, kv.x}, ky = (v2f){kv.y, kv.y},
                  kz = (v2f){kv.z, kv.z}, kw = (v2f){kv.w, kv.w};
        const v2f ux = (v2f){uv.x, uv.x}, uy = (v2f){uv.y, uv.y},
                  uz = (v2f){uv.z, uv.z}, uw = (v2f){uv.w, uv.w};
        #pragma unroll
        for (int p = 0; p < 4; ++p) {
            v2f s = qv[p][3] * kw;
            s = __builtin_elementwise_fma(qv[p][2], kz, s);
            s = __builtin_elementwise_fma(qv[p][1], ky, s);
            s = __builtin_elementwise_fma(qv[p][0], kx, s);
            v2f e;
            e.x = EXP2(s.x);
            e.y = EXP2(s.y);
            l2[p] += e;
            a2[p][0] = __builtin_elementwise_fma(e, ux, a2[p][0]);
            a2[p][1] = __builtin_elementwise_fma(e, uy, a2[p][1]);
            a2[p][2] = __builtin_elementwise_fma(e, uz, a2[p][2]);
            a2[p][3] = __builtin_elementwise_fma(e, uw, a2[p][3]);
        }
    }

    // ---- butterfly over the c-octet (combine 8 chunks) ----
    #pragma unroll
    for (int m = 1; m <= 4; m <<= 1) {
        #pragma unroll
        for (int p = 0; p < 4; ++p) {
            l2[p].x += __shfl_xor(l2[p].x, m);
            l2[p].y += __shfl_xor(l2[p].y, m);
            #pragma unroll
            for (int d = 0; d < DPH; ++d) {
                a2[p][d].x += __shfl_xor(a2[p][d].x, m);
                a2[p][d].y += __shfl_xor(a2[p][d].y, m);
            }
        }
    }

    // ---- lane selects row-slot 8g + c (static unroll) ----
    float lsel = l2[0].x, p0 = a2[0][0].x, p1 = a2[0][1].x,
          p2 = a2[0][2].x, p3 = a2[0][3].x;
    #pragma unroll
    for (int r = 1; r < 8; ++r) {
        if (r == c) {
            const int pp = r >> 1;
            if (r & 1) {
                lsel = l2[pp].y; p0 = a2[pp][0].y; p1 = a2[pp][1].y;
                p2 = a2[pp][2].y; p3 = a2[pp][3].y;
            } else {
                lsel = l2[pp].x; p0 = a2[pp][0].x; p1 = a2[pp][1].x;
                p2 = a2[pp][2].x; p3 = a2[pp][3].x;
            }
        }
    }

    const int slot = 8 * g + c;
    if (slot < Nk) {
        const int row = rlist[slot];
        const size_t idx = (((size_t)(b * NE + row)) * NH + h) * 2 + kh;
        attp[idx] = make_float4(p0, p1, p2, p3);   // unscaled partial sums
        lp[idx]   = lsel - padcorr;                // pad-corrected partial l
    }
}

// ---------------------------------------------------------------------------
// epilogue: merge K-half partials (exact reassociation), post-proj + residual,
// mask-corrected norm, masked mean pool. Masked rows: scale = 0/(finite) = 0,
// so 0xAA-poisoned unwritten partials are harmless.
// ---------------------------------------------------------------------------
__global__ __launch_bounds__(NE) void epi_kernel(
    const float* __restrict__ inp, const float* __restrict__ mask,
    const float* __restrict__ Wpost,
    const float4* __restrict__ attp, const float* __restrict__ lpa,
    float* __restrict__ out)
{
    const int b = blockIdx.x;
    const int i = threadIdx.x;
    const int wave = i >> 6;
    const int lane = i & 63;

    __shared__ float swp[F * NEMBD];
    __shared__ float red[64];

    if (i < F * NEMBD) swp[i] = Wpost[i];
    __syncthreads();

    const float mi = mask[b * NE + i];
    const float* row = inp + ((size_t)(b * NE + i)) * F;
    const float4* ap = attp + ((size_t)(b * NE + i)) * NH * 2;
    const float*  lr = lpa  + ((size_t)(b * NE + i)) * NH * 2;

    float a[NEMBD];
    #pragma unroll
    for (int h = 0; h < NH; ++h) {
        const float4 s0 = ap[2 * h], s1 = ap[2 * h + 1];
        const float  l  = lr[2 * h] + lr[2 * h + 1];
        const float  sc = mi / l;                  // masked row: 0/finite = 0
        a[4*h+0] = (s0.x + s1.x) * sc;
        a[4*h+1] = (s0.y + s1.y) * sc;
        a[4*h+2] = (s0.z + s1.z) * sc;
        a[4*h+3] = (s0.w + s1.w) * sc;
    }

    float x[F];
    #pragma unroll
    for (int f = 0; f < F; ++f) {
        float acc = row[f] * mi;
        #pragma unroll
        for (int t = 0; t < NEMBD; ++t) acc = fmaf(a[t], swp[f * NEMBD + t], acc);
        x[f] = acc;
    }

    // ---- phase 1: S = sum(x), N = sum(mask) ----
    float rsum = x[0] + x[1] + x[2] + x[3] + x[4] + x[5];
    float rn = mi;
    #pragma unroll
    for (int off = 32; off >= 1; off >>= 1) {
        rsum += __shfl_down(rsum, off);
        rn   += __shfl_down(rn, off);
    }
    if (lane == 0) { red[wave * 2] = rsum; red[wave * 2 + 1] = rn; }
    __syncthreads();
    float S = 0.f, N = 0.f;
    #pragma unroll
    for (int w = 0; w < 8; ++w) { S += red[w * 2]; N += red[w * 2 + 1]; }

    const float mu     = S / (6.0f * N);
    const float sum_x2 = S + (NE - N) * 6.0f * mu;
    const float m2     = sum_x2 / (NE * 6.0f);
    const float add    = (1.0f - mi) * mu;

    float ss = 0.f;
    #pragma unroll
    for (int f = 0; f < F; ++f) { const float d = x[f] + add - m2; ss = fmaf(d, d, ss); }

    // ---- phase 2: sum of squares ----
    __syncthreads();
    #pragma unroll
    for (int off = 32; off >= 1; off >>= 1) ss += __shfl_down(ss, off);
    if (lane == 0) red[wave] = ss;
    __syncthreads();
    float vs = 0.f;
    #pragma unroll
    for (int w = 0; w < 8; ++w) vs += red[w];

    const float var  = vs / (NE * 6.0f - 1.0f);
    const float stdv = sqrtf(var) * sqrtf((6.0f * NE - 1.0f) / (6.0f * N - 1.0f));
    const float inv  = 1.0f / (stdv + 1e-6f);

    float y[F];
    #pragma unroll
    for (int f = 0; f < F; ++f) y[f] = mi * (x[f] - mu) * inv;

    // ---- phase 3: 6 masked feature sums ----
    __syncthreads();
    #pragma unroll
    for (int off = 32; off >= 1; off >>= 1) {
        #pragma unroll
        for (int f = 0; f < F; ++f) y[f] += __shfl_down(y[f], off);
    }
    if (lane == 0) {
        #pragma unroll
        for (int f = 0; f < F; ++f) red[wave * F + f] = y[f];
    }
    __syncthreads();
    if (i < F) {
        float tt = 0.f;
        #pragma unroll
        for (int w = 0; w < 8; ++w) tt += red[w * F + i];
        out[b * F + i] = tt / N;
    }
}

// ---------------------------------------------------------------------------
extern "C" void kernel_launch(void* const* d_in, const int* in_sizes, int n_in,
                              void* d_out, int out_size, void* d_ws, size_t ws_size,
                              hipStream_t stream) {
    const float* inp   = (const float*)d_in[0];
    const float* mask  = (const float*)d_in[1];
    const float* Wq    = (const float*)d_in[2];
    const float* Wk    = (const float*)d_in[3];
    const float* Wv    = (const float*)d_in[4];
    const float* Wpost = (const float*)d_in[5];
    float* out = (float*)d_out;

    float4* attp = (float4*)d_ws;                           // 8 MB
    float*  lp   = (float*)((char*)d_ws + (size_t)BS * NE * NH * 2 * sizeof(float4));  // 2 MB

    attn_kernel<<<BS * NH * 2, 512, 0, stream>>>(inp, mask, Wq, Wk, Wv, attp, lp);
    epi_kernel <<<BS, NE, 0, stream>>>(inp, mask, Wpost, attp, lp, out);
}